// Round 4
// baseline (43.227 us; speedup 1.0000x reference)
//
#include <hip/hip_runtime.h>

#define OUT_H 256
#define OUT_W 192
#define NPIX  (OUT_H * OUT_W)   // 49152
#define NB    256
#define NC    25                 // N_CTRL
#define NL    28                 // NC + 3
#define BCHUNK 32

typedef float f2_t __attribute__((ext_vector_type(2)));

// ---------------------------------------------------------------------------
// Compile-time Li = inv(L) (first NC columns), fp64 Gauss-Jordan w/ partial
// pivoting, evaluated by the compiler. cx_log: ln via atanh series (~1e-16).
// ---------------------------------------------------------------------------
constexpr double cx_log(double x) {
    int k = 0;
    while (x > 1.5) { x *= 0.5; ++k; }
    while (x < 0.75) { x *= 2.0; --k; }
    double z = (x - 1.0) / (x + 1.0);
    double z2 = z * z;
    double t = z, s = 0.0;
    for (int i = 0; i < 16; ++i) { s += t / (double)(2 * i + 1); t *= z2; }
    return 2.0 * s + (double)k * 0.69314718055994530941723212145817656808;
}

struct LiMat { float v[NL][NC]; };

constexpr LiMat make_li() {
    double aug[NL][2 * NL] = {};
    const double ax[5] = {-1.0, -0.5, 0.0, 0.5, 1.0};
    for (int i = 0; i < NL; ++i)
        for (int j = 0; j < NL; ++j) {
            double v = 0.0;
            if (i < NC && j < NC) {
                double dx = ax[i / 5] - ax[j / 5];
                double dy = ax[i % 5] - ax[j % 5];
                double d2 = dx * dx + dy * dy;
                v = (d2 == 0.0) ? 0.0 : d2 * cx_log(d2);
            } else if (i < NC) {
                v = (j == NC) ? 1.0 : ((j == NC + 1) ? ax[i / 5] : ax[i % 5]);
            } else if (j < NC) {
                v = (i == NC) ? 1.0 : ((i == NC + 1) ? ax[j / 5] : ax[j % 5]);
            }
            aug[i][j] = (double)(float)v;   // mimic numpy's fp32 L build
        }
    for (int i = 0; i < NL; ++i) aug[i][NL + i] = 1.0;

    for (int k = 0; k < NL; ++k) {
        int p = k;
        double best = aug[k][k] < 0 ? -aug[k][k] : aug[k][k];
        for (int r = k + 1; r < NL; ++r) {
            double a = aug[r][k] < 0 ? -aug[r][k] : aug[r][k];
            if (a > best) { best = a; p = r; }
        }
        if (p != k)
            for (int j = k; j < 2 * NL; ++j) {
                double t = aug[k][j]; aug[k][j] = aug[p][j]; aug[p][j] = t;
            }
        const double ipv = 1.0 / aug[k][k];
        for (int j = k; j < 2 * NL; ++j) aug[k][j] *= ipv;
        for (int r = 0; r < NL; ++r) {
            if (r == k) continue;
            const double f = aug[r][k];
            if (f == 0.0) continue;
            for (int j = k; j < 2 * NL; ++j) aug[r][j] -= f * aug[k][j];
        }
    }
    LiMat o = {};
    for (int i = 0; i < NL; ++i)
        for (int j = 0; j < NC; ++j)
            o.v[i][j] = (float)aug[i][NL + j];
    return o;
}

constexpr LiMat LI_HOST = make_li();
__constant__ LiMat LI = LI_HOST;          // 2.8 KB, baked at compile time
__constant__ float WC[NB * 64];           // 64 KB, written by tps_coeff each call
// per-batch layout (stride 64): [0..24]=WX [25..49]=WY [50..52]=AX [53..55]=AY

// ---------------------------------------------------------------------------
// Per-batch coefficients. 4 blocks x 64 threads; thread = one batch.
// theta staged through LDS for coalesced global reads; Li via s_load.
// ---------------------------------------------------------------------------
__global__ __launch_bounds__(64) void tps_coeff(const float* __restrict__ theta,
                                                float* __restrict__ wc) {
    __shared__ float sth[64 * 2 * NC];
    const int t = threadIdx.x;
    const int gbase = blockIdx.x * 64 * 2 * NC;
    #pragma unroll
    for (int k = 0; k < 2 * NC; ++k) {
        const int idx = k * 64 + t;
        sth[idx] = theta[gbase + idx];
    }
    __syncthreads();

    const float axf[5] = {-1.f, -0.5f, 0.f, 0.5f, 1.f};
    float q[2 * NC];
    #pragma unroll
    for (int m = 0; m < NC; ++m) {
        q[m]      = sth[t * 2 * NC + m]      + axf[m / 5];
        q[NC + m] = sth[t * 2 * NC + NC + m] + axf[m % 5];
    }

    float* wb = wc + ((blockIdx.x * 64 + t) << 6);
    #pragma unroll
    for (int n = 0; n < NL; ++n) {
        float sx = 0.f, sy = 0.f;
        #pragma unroll
        for (int m = 0; m < NC; ++m) {
            const float l = LI.v[n][m];
            sx = fmaf(l, q[m],      sx);
            sy = fmaf(l, q[NC + m], sy);
        }
        if (n < NC) { wb[n] = sx; wb[NC + n] = sy; }
        else        { wb[50 + (n - NC)] = sx; wb[53 + (n - NC)] = sy; }
    }
}

// ---------------------------------------------------------------------------
// Main evaluation. grid = (192, 8), 256 threads; 1 pixel/thread, U[25] in
// registers reused over BCHUNK=32 batches. 6 waves/SIMD for store-latency
// hiding. Coefficients via __constant__ s_loads; native v_log_f32.
// float2 nontemporal coalesced stores.
// ---------------------------------------------------------------------------
__global__ __launch_bounds__(256) void tps_main(f2_t* __restrict__ out2) {
    const int p = blockIdx.x * 256 + threadIdx.x;      // pixel 0..49151
    const int h = p / OUT_W;
    const int w = p - h * OUT_W;

    const float gy = (h == OUT_H - 1) ? 1.f : (float)(-1.0 + h * (2.0 / (OUT_H - 1)));
    const float gx = (w == OUT_W - 1) ? 1.f : (float)(-1.0 + w * (2.0 / (OUT_W - 1)));

    const float axf[5] = {-1.f, -0.5f, 0.f, 0.5f, 1.f};
    float U[NC];
    #pragma unroll
    for (int n = 0; n < NC; ++n) {
        const float dx = gx - axf[n / 5];
        const float dy = gy - axf[n % 5];
        const float d2 = dx * dx + dy * dy;
        U[n] = (d2 == 0.f) ? 0.f : d2 * __logf(d2);
    }

    const int b0 = blockIdx.y * BCHUNK;
    for (int bi = 0; bi < BCHUNK; ++bi) {
        const int b = b0 + bi;
        const int o = b << 6;
        float X = fmaf(WC[o + 52], gy, fmaf(WC[o + 51], gx, WC[o + 50]));
        float Y = fmaf(WC[o + 55], gy, fmaf(WC[o + 54], gx, WC[o + 53]));
        #pragma unroll
        for (int n = 0; n < NC; ++n) {
            X = fmaf(U[n], WC[o + n],      X);
            Y = fmaf(U[n], WC[o + NC + n], Y);
        }
        f2_t v; v.x = X; v.y = Y;
        __builtin_nontemporal_store(v, &out2[(size_t)b * NPIX + p]);
    }
}

// ---------------------------------------------------------------------------
extern "C" void kernel_launch(void* const* d_in, const int* in_sizes, int n_in,
                              void* d_out, int out_size, void* d_ws, size_t ws_size,
                              hipStream_t stream) {
    const float* theta = (const float*)d_in[0];

    void* wcsym = nullptr;
    hipGetSymbolAddress(&wcsym, HIP_SYMBOL(WC));   // host-side query, capture-safe

    tps_coeff<<<NB / 64, 64, 0, stream>>>(theta, (float*)wcsym);
    dim3 grid(NPIX / 256, NB / BCHUNK);            // (192, 8)
    tps_main<<<grid, 256, 0, stream>>>((f2_t*)d_out);
}

// Round 5
// 42.121 us; speedup vs baseline: 1.0263x; 1.0263x over previous
//
#include <hip/hip_runtime.h>

#define OUT_H 256
#define OUT_W 192
#define NPIX  (OUT_H * OUT_W)   // 49152
#define NB    256
#define NC    25                 // N_CTRL
#define NL    28                 // NC + 3
#define BCHUNK 16

typedef float f4_t __attribute__((ext_vector_type(4)));

// ---------------------------------------------------------------------------
// Compile-time Li = inv(L) (first NC columns), fp64 Gauss-Jordan w/ partial
// pivoting, evaluated by the compiler. cx_log: ln via atanh series (~1e-16).
// ---------------------------------------------------------------------------
constexpr double cx_log(double x) {
    int k = 0;
    while (x > 1.5) { x *= 0.5; ++k; }
    while (x < 0.75) { x *= 2.0; --k; }
    double z = (x - 1.0) / (x + 1.0);
    double z2 = z * z;
    double t = z, s = 0.0;
    for (int i = 0; i < 16; ++i) { s += t / (double)(2 * i + 1); t *= z2; }
    return 2.0 * s + (double)k * 0.69314718055994530941723212145817656808;
}

struct LiMat { float v[NL][NC]; };

constexpr LiMat make_li() {
    double aug[NL][2 * NL] = {};
    const double ax[5] = {-1.0, -0.5, 0.0, 0.5, 1.0};
    for (int i = 0; i < NL; ++i)
        for (int j = 0; j < NL; ++j) {
            double v = 0.0;
            if (i < NC && j < NC) {
                double dx = ax[i / 5] - ax[j / 5];
                double dy = ax[i % 5] - ax[j % 5];
                double d2 = dx * dx + dy * dy;
                v = (d2 == 0.0) ? 0.0 : d2 * cx_log(d2);
            } else if (i < NC) {
                v = (j == NC) ? 1.0 : ((j == NC + 1) ? ax[i / 5] : ax[i % 5]);
            } else if (j < NC) {
                v = (i == NC) ? 1.0 : ((i == NC + 1) ? ax[j / 5] : ax[j % 5]);
            }
            aug[i][j] = (double)(float)v;   // mimic numpy's fp32 L build
        }
    for (int i = 0; i < NL; ++i) aug[i][NL + i] = 1.0;

    for (int k = 0; k < NL; ++k) {
        int p = k;
        double best = aug[k][k] < 0 ? -aug[k][k] : aug[k][k];
        for (int r = k + 1; r < NL; ++r) {
            double a = aug[r][k] < 0 ? -aug[r][k] : aug[r][k];
            if (a > best) { best = a; p = r; }
        }
        if (p != k)
            for (int j = k; j < 2 * NL; ++j) {
                double t = aug[k][j]; aug[k][j] = aug[p][j]; aug[p][j] = t;
            }
        const double ipv = 1.0 / aug[k][k];
        for (int j = k; j < 2 * NL; ++j) aug[k][j] *= ipv;
        for (int r = 0; r < NL; ++r) {
            if (r == k) continue;
            const double f = aug[r][k];
            if (f == 0.0) continue;
            for (int j = k; j < 2 * NL; ++j) aug[r][j] -= f * aug[k][j];
        }
    }
    LiMat o = {};
    for (int i = 0; i < NL; ++i)
        for (int j = 0; j < NC; ++j)
            o.v[i][j] = (float)aug[i][NL + j];
    return o;
}

constexpr LiMat LI_HOST = make_li();
__constant__ LiMat LI = LI_HOST;          // 2.8 KB, baked at compile time
__constant__ float WC[NB * 64];           // 64 KB, written by tps_coeff each call
// per-batch layout (stride 64): [0..24]=WX [25..49]=WY [50..52]=AX [53..55]=AY

// ---------------------------------------------------------------------------
// Per-batch coefficients. 4 blocks x 64 threads; thread = one batch.
// ---------------------------------------------------------------------------
__global__ __launch_bounds__(64) void tps_coeff(const float* __restrict__ theta,
                                                float* __restrict__ wc) {
    __shared__ float sth[64 * 2 * NC];
    const int t = threadIdx.x;
    const int gbase = blockIdx.x * 64 * 2 * NC;
    #pragma unroll
    for (int k = 0; k < 2 * NC; ++k) {
        const int idx = k * 64 + t;
        sth[idx] = theta[gbase + idx];
    }
    __syncthreads();

    const float axf[5] = {-1.f, -0.5f, 0.f, 0.5f, 1.f};
    float q[2 * NC];
    #pragma unroll
    for (int m = 0; m < NC; ++m) {
        q[m]      = sth[t * 2 * NC + m]      + axf[m / 5];
        q[NC + m] = sth[t * 2 * NC + NC + m] + axf[m % 5];
    }

    float* wb = wc + ((blockIdx.x * 64 + t) << 6);
    #pragma unroll
    for (int n = 0; n < NL; ++n) {
        float sx = 0.f, sy = 0.f;
        #pragma unroll
        for (int m = 0; m < NC; ++m) {
            const float l = LI.v[n][m];
            sx = fmaf(l, q[m],      sx);
            sy = fmaf(l, q[NC + m], sy);
        }
        if (n < NC) { wb[n] = sx; wb[NC + n] = sy; }
        else        { wb[50 + (n - NC)] = sx; wb[53 + (n - NC)] = sy; }
    }
}

// ---------------------------------------------------------------------------
// Main evaluation. grid = (96, 16), 256 threads. Two adjacent pixels per
// thread -> full-width dwordx4 stores (1024 B/wave-store, like the 6.9 TB/s
// fill kernel). BCHUNK=16 -> 1536 blocks = 6 waves/SIMD for latency hiding.
// Plain cached stores (NT hint removed: A/B vs R3 showed store path is
// sensitive; fill kernels use cached stores). Coeffs via __constant__ s_load.
// ---------------------------------------------------------------------------
__global__ __launch_bounds__(256) void tps_main(f4_t* __restrict__ out4) {
    const int pp = blockIdx.x * 256 + threadIdx.x;     // pixel-pair 0..24575
    const int h  = pp / (OUT_W / 2);
    const int w0 = (pp - h * (OUT_W / 2)) * 2;

    const float gy  = (h == OUT_H - 1) ? 1.f : (float)(-1.0 + h * (2.0 / (OUT_H - 1)));
    const float gx0 = (float)(-1.0 + w0 * (2.0 / (OUT_W - 1)));
    const float gx1 = (w0 + 1 == OUT_W - 1) ? 1.f
                                            : (float)(-1.0 + (w0 + 1) * (2.0 / (OUT_W - 1)));

    const float axf[5] = {-1.f, -0.5f, 0.f, 0.5f, 1.f};
    float U0[NC], U1[NC];
    #pragma unroll
    for (int n = 0; n < NC; ++n) {
        const float cx = axf[n / 5], cy = axf[n % 5];
        const float dy  = gy - cy;
        const float dx0 = gx0 - cx;
        const float d20 = dx0 * dx0 + dy * dy;
        U0[n] = (d20 == 0.f) ? 0.f : d20 * __logf(d20);
        const float dx1 = gx1 - cx;
        const float d21 = dx1 * dx1 + dy * dy;
        U1[n] = (d21 == 0.f) ? 0.f : d21 * __logf(d21);
    }

    const int b0 = blockIdx.y * BCHUNK;
    for (int bi = 0; bi < BCHUNK; ++bi) {
        const int b = b0 + bi;
        const int o = b << 6;
        float X0 = fmaf(WC[o + 52], gy, fmaf(WC[o + 51], gx0, WC[o + 50]));
        float X1 = fmaf(WC[o + 52], gy, fmaf(WC[o + 51], gx1, WC[o + 50]));
        float Y0 = fmaf(WC[o + 55], gy, fmaf(WC[o + 54], gx0, WC[o + 53]));
        float Y1 = fmaf(WC[o + 55], gy, fmaf(WC[o + 54], gx1, WC[o + 53]));
        #pragma unroll
        for (int n = 0; n < NC; ++n) {
            const float wx = WC[o + n];
            const float wy = WC[o + NC + n];
            X0 = fmaf(U0[n], wx, X0);
            X1 = fmaf(U1[n], wx, X1);
            Y0 = fmaf(U0[n], wy, Y0);
            Y1 = fmaf(U1[n], wy, Y1);
        }
        f4_t v; v.x = X0; v.y = Y0; v.z = X1; v.w = Y1;
        out4[(size_t)b * (NPIX / 2) + pp] = v;
    }
}

// ---------------------------------------------------------------------------
extern "C" void kernel_launch(void* const* d_in, const int* in_sizes, int n_in,
                              void* d_out, int out_size, void* d_ws, size_t ws_size,
                              hipStream_t stream) {
    const float* theta = (const float*)d_in[0];

    void* wcsym = nullptr;
    hipGetSymbolAddress(&wcsym, HIP_SYMBOL(WC));   // host-side query, capture-safe

    tps_coeff<<<NB / 64, 64, 0, stream>>>(theta, (float*)wcsym);
    dim3 grid(NPIX / 2 / 256, NB / BCHUNK);        // (96, 16)
    tps_main<<<grid, 256, 0, stream>>>((f4_t*)d_out);
}

// Round 6
// 35.730 us; speedup vs baseline: 1.2098x; 1.1789x over previous
//
#include <hip/hip_runtime.h>

#define OUT_H 256
#define OUT_W 192
#define NPIX  (OUT_H * OUT_W)   // 49152
#define NPP   (NPIX / 2)        // 24576 pixel-pairs
#define NB    256
#define NC    25                 // N_CTRL
#define NL    28                 // NC + 3
#define BCHUNK 32

typedef float f4_t __attribute__((ext_vector_type(4)));

// ---------------------------------------------------------------------------
// Compile-time Li = inv(L) (first NC columns), fp64 Gauss-Jordan w/ partial
// pivoting, evaluated by the compiler. cx_log: ln via atanh series (~1e-16).
// ---------------------------------------------------------------------------
constexpr double cx_log(double x) {
    int k = 0;
    while (x > 1.5) { x *= 0.5; ++k; }
    while (x < 0.75) { x *= 2.0; --k; }
    double z = (x - 1.0) / (x + 1.0);
    double z2 = z * z;
    double t = z, s = 0.0;
    for (int i = 0; i < 16; ++i) { s += t / (double)(2 * i + 1); t *= z2; }
    return 2.0 * s + (double)k * 0.69314718055994530941723212145817656808;
}

struct LiMat { float v[NL][NC]; };

constexpr LiMat make_li() {
    double aug[NL][2 * NL] = {};
    const double ax[5] = {-1.0, -0.5, 0.0, 0.5, 1.0};
    for (int i = 0; i < NL; ++i)
        for (int j = 0; j < NL; ++j) {
            double v = 0.0;
            if (i < NC && j < NC) {
                double dx = ax[i / 5] - ax[j / 5];
                double dy = ax[i % 5] - ax[j % 5];
                double d2 = dx * dx + dy * dy;
                v = (d2 == 0.0) ? 0.0 : d2 * cx_log(d2);
            } else if (i < NC) {
                v = (j == NC) ? 1.0 : ((j == NC + 1) ? ax[i / 5] : ax[i % 5]);
            } else if (j < NC) {
                v = (i == NC) ? 1.0 : ((i == NC + 1) ? ax[j / 5] : ax[j % 5]);
            }
            aug[i][j] = (double)(float)v;   // mimic numpy's fp32 L build
        }
    for (int i = 0; i < NL; ++i) aug[i][NL + i] = 1.0;

    for (int k = 0; k < NL; ++k) {
        int p = k;
        double best = aug[k][k] < 0 ? -aug[k][k] : aug[k][k];
        for (int r = k + 1; r < NL; ++r) {
            double a = aug[r][k] < 0 ? -aug[r][k] : aug[r][k];
            if (a > best) { best = a; p = r; }
        }
        if (p != k)
            for (int j = k; j < 2 * NL; ++j) {
                double t = aug[k][j]; aug[k][j] = aug[p][j]; aug[p][j] = t;
            }
        const double ipv = 1.0 / aug[k][k];
        for (int j = k; j < 2 * NL; ++j) aug[k][j] *= ipv;
        for (int r = 0; r < NL; ++r) {
            if (r == k) continue;
            const double f = aug[r][k];
            if (f == 0.0) continue;
            for (int j = k; j < 2 * NL; ++j) aug[r][j] -= f * aug[k][j];
        }
    }
    LiMat o = {};
    for (int i = 0; i < NL; ++i)
        for (int j = 0; j < NC; ++j)
            o.v[i][j] = (float)aug[i][NL + j];
    return o;
}

constexpr LiMat LI_HOST = make_li();
__constant__ LiMat LI = LI_HOST;          // 2.8 KB, baked at compile time

// ---------------------------------------------------------------------------
// Single fused kernel. grid = (96, 8), 256 threads.
//  Prologue (per block, ~0.5 us): stage theta slice (32 batches x 50) -> LDS,
//    compute the 32x56 coefficient block cooperatively (7 rows of Li per
//    thread-group), store to LDS.
//  Main loop: 2 adjacent pixels/thread, U[25]x2 in registers, 32 batches;
//    coefficients read as broadcast ds_read_b128 (conflict-free);
//    float4 nontemporal stores (R3 config: best measured store path).
//  swc row layout (stride 56): [0..24]=WX [25..49]=WY [50..52]=AX [53..55]=AY
// ---------------------------------------------------------------------------
__global__ __launch_bounds__(256) void tps_fused(const float* __restrict__ theta,
                                                 f4_t* __restrict__ out4) {
    __shared__ float sth[BCHUNK * 2 * NC];   // 1600 floats
    __shared__ float swc[BCHUNK][56];        // 32 x 56 coeffs (224B rows, 16B-aligned)

    const int tid = threadIdx.x;
    const int b0  = blockIdx.y * BCHUNK;

    // ---- stage theta slice (coalesced) ----
    #pragma unroll
    for (int k = 0; k < BCHUNK * 2 * NC; k += 256) {
        const int idx = k + tid;
        if (idx < BCHUNK * 2 * NC) sth[idx] = theta[b0 * 2 * NC + idx];
    }
    __syncthreads();

    const float axf[5] = {-1.f, -0.5f, 0.f, 0.5f, 1.f};

    // ---- coefficient block: b = tid>>3, group g = tid&7 handles rows 4g..4g+3
    {
        const int b = tid >> 3;
        const int g = tid & 7;
        if (g < 7) {
            float qx[NC], qy[NC];
            #pragma unroll
            for (int m = 0; m < NC; ++m) {
                qx[m] = sth[b * 2 * NC + m]      + axf[m / 5];
                qy[m] = sth[b * 2 * NC + NC + m] + axf[m % 5];
            }
            #pragma unroll
            for (int r = 0; r < 4; ++r) {
                const int n = g * 4 + r;
                float sx = 0.f, sy = 0.f;
                #pragma unroll
                for (int m = 0; m < NC; ++m) {
                    const float l = LI.v[n][m];
                    sx = fmaf(l, qx[m], sx);
                    sy = fmaf(l, qy[m], sy);
                }
                if (n < NC) { swc[b][n] = sx;              swc[b][NC + n] = sy; }
                else        { swc[b][50 + (n - NC)] = sx;  swc[b][53 + (n - NC)] = sy; }
            }
        }
    }

    // ---- per-thread radial basis for 2 adjacent pixels ----
    const int pp = blockIdx.x * 256 + tid;           // pixel-pair 0..24575
    const int h  = pp / (OUT_W / 2);
    const int w0 = (pp - h * (OUT_W / 2)) * 2;

    const float gy  = (h == OUT_H - 1) ? 1.f : (float)(-1.0 + h * (2.0 / (OUT_H - 1)));
    const float gx0 = (float)(-1.0 + w0 * (2.0 / (OUT_W - 1)));
    const float gx1 = (w0 + 1 == OUT_W - 1) ? 1.f
                                            : (float)(-1.0 + (w0 + 1) * (2.0 / (OUT_W - 1)));

    float U0[NC], U1[NC];
    #pragma unroll
    for (int n = 0; n < NC; ++n) {
        const float cx = axf[n / 5], cy = axf[n % 5];
        const float dy  = gy - cy;
        const float dx0 = gx0 - cx;
        const float d20 = dx0 * dx0 + dy * dy;
        U0[n] = (d20 == 0.f) ? 0.f : d20 * __logf(d20);
        const float dx1 = gx1 - cx;
        const float d21 = dx1 * dx1 + dy * dy;
        U1[n] = (d21 == 0.f) ? 0.f : d21 * __logf(d21);
    }

    __syncthreads();

    // ---- main loop over the block's 32 batches ----
    for (int bi = 0; bi < BCHUNK; ++bi) {
        float c[56];
        #pragma unroll
        for (int k = 0; k < 14; ++k)
            *(f4_t*)&c[k * 4] = *(const f4_t*)&swc[bi][k * 4];   // broadcast b128

        float X0 = fmaf(c[52], gy, fmaf(c[51], gx0, c[50]));
        float X1 = fmaf(c[52], gy, fmaf(c[51], gx1, c[50]));
        float Y0 = fmaf(c[55], gy, fmaf(c[54], gx0, c[53]));
        float Y1 = fmaf(c[55], gy, fmaf(c[54], gx1, c[53]));
        #pragma unroll
        for (int n = 0; n < NC; ++n) {
            X0 = fmaf(U0[n], c[n],      X0);
            X1 = fmaf(U1[n], c[n],      X1);
            Y0 = fmaf(U0[n], c[NC + n], Y0);
            Y1 = fmaf(U1[n], c[NC + n], Y1);
        }
        f4_t v; v.x = X0; v.y = Y0; v.z = X1; v.w = Y1;
        __builtin_nontemporal_store(v, &out4[(size_t)(b0 + bi) * NPP + pp]);
    }
}

// ---------------------------------------------------------------------------
extern "C" void kernel_launch(void* const* d_in, const int* in_sizes, int n_in,
                              void* d_out, int out_size, void* d_ws, size_t ws_size,
                              hipStream_t stream) {
    const float* theta = (const float*)d_in[0];
    dim3 grid(NPP / 256, NB / BCHUNK);             // (96, 8) = 768 blocks
    tps_fused<<<grid, 256, 0, stream>>>(theta, (f4_t*)d_out);
}